// Round 2
// baseline (3131.230 us; speedup 1.0000x reference)
//
#include <hip/hip_runtime.h>

// Problem constants
#define B_  4
#define T_  2048
#define C_  1024
#define NH_ 16
#define HD_ 64
#define BT_ (B_*T_)   // 8192
#define N3C (3*C_)    // 3072

// ---------------------------------------------------------------------------
// Kernel 1: qkv = x @ w_attn + b_attn, scattered to q/k/v in (B,NH,T,HD) fp32.
// 64x64 tile, BK=32, 256 threads, 4x4 per thread, fp32 accumulate.
// ---------------------------------------------------------------------------
__global__ __launch_bounds__(256) void gemm_qkv(
    const float* __restrict__ X, const float* __restrict__ W,
    const float* __restrict__ bias,
    float* __restrict__ Qo, float* __restrict__ Ko, float* __restrict__ Vo)
{
  __shared__ float As[32][68];   // [k][m], +4 pad keeps 16B alignment
  __shared__ float Bs[32][68];   // [k][n]
  const int tid  = threadIdx.x;
  const int row0 = blockIdx.y * 64;
  const int col0 = blockIdx.x * 64;
  const int tx = tid & 15, ty = tid >> 4;
  const int am = tid >> 2, ak = (tid & 3) * 8;   // A loader: row am, k's ak..ak+7
  const int bk = tid >> 3, bn = (tid & 7) * 8;   // B loader: k bk, n's bn..bn+7
  float acc[4][4] = {};

  for (int k0 = 0; k0 < C_; k0 += 32) {
    const float4 a0 = *(const float4*)(X + (size_t)(row0 + am) * C_ + k0 + ak);
    const float4 a1 = *(const float4*)(X + (size_t)(row0 + am) * C_ + k0 + ak + 4);
    const float4 b0 = *(const float4*)(W + (size_t)(k0 + bk) * N3C + col0 + bn);
    const float4 b1 = *(const float4*)(W + (size_t)(k0 + bk) * N3C + col0 + bn + 4);
    As[ak + 0][am] = a0.x; As[ak + 1][am] = a0.y;
    As[ak + 2][am] = a0.z; As[ak + 3][am] = a0.w;
    As[ak + 4][am] = a1.x; As[ak + 5][am] = a1.y;
    As[ak + 6][am] = a1.z; As[ak + 7][am] = a1.w;
    *(float4*)&Bs[bk][bn]     = b0;
    *(float4*)&Bs[bk][bn + 4] = b1;
    __syncthreads();
#pragma unroll
    for (int kk = 0; kk < 32; ++kk) {
      float va0 = As[kk][ty*4+0], va1 = As[kk][ty*4+1],
            va2 = As[kk][ty*4+2], va3 = As[kk][ty*4+3];
      float vb0 = Bs[kk][tx*4+0], vb1 = Bs[kk][tx*4+1],
            vb2 = Bs[kk][tx*4+2], vb3 = Bs[kk][tx*4+3];
      acc[0][0] += va0*vb0; acc[0][1] += va0*vb1; acc[0][2] += va0*vb2; acc[0][3] += va0*vb3;
      acc[1][0] += va1*vb0; acc[1][1] += va1*vb1; acc[1][2] += va1*vb2; acc[1][3] += va1*vb3;
      acc[2][0] += va2*vb0; acc[2][1] += va2*vb1; acc[2][2] += va2*vb2; acc[2][3] += va2*vb3;
      acc[3][0] += va3*vb0; acc[3][1] += va3*vb1; acc[3][2] += va3*vb2; acc[3][3] += va3*vb3;
    }
    __syncthreads();
  }

  // Epilogue: each tile covers exactly one region (q/k/v) and one head.
  const int region = col0 >> 10;           // 0=q 1=k 2=v
  const int h      = (col0 & 1023) >> 6;
  float* dst = (region == 0) ? Qo : ((region == 1) ? Ko : Vo);
#pragma unroll
  for (int i = 0; i < 4; ++i) {
    const int r = row0 + ty * 4 + i;
    const int b = r >> 11, t = r & (T_ - 1);
    const size_t base = ((size_t)(b * NH_ + h) * T_ + t) * HD_;
#pragma unroll
    for (int j = 0; j < 4; ++j) {
      const int d = tx * 4 + j;
      dst[base + d] = acc[i][j] + bias[col0 + d];
    }
  }
}

// ---------------------------------------------------------------------------
// Kernel 2: in-place RoPE on q and k. One thread per (row, f<32) pair.
// ---------------------------------------------------------------------------
__global__ __launch_bounds__(256) void rope_qk(float* __restrict__ Q,
                                               float* __restrict__ Ko)
{
  const int idx = blockIdx.x * 256 + threadIdx.x;   // < B*NH*T*32
  const int f   = idx & 31;
  const int row = idx >> 5;                         // (b*NH+h)*T + t
  const int t   = row & (T_ - 1);
  // inv_freq = 10000^(-2f/64), angle = t * inv_freq
  const float e   = (float)(2 * f) * (1.0f / 64.0f);
  const float inv = expf(-e * 9.210340371976184f);  // ln(10000)
  const float ang = (float)t * inv;
  float sn, cn;
  sincosf(ang, &sn, &cn);

  const size_t p = (size_t)row * HD_ + f;
  {
    float x1 = Q[p], x2 = Q[p + 32];
    Q[p]      = x1 * cn - x2 * sn;
    Q[p + 32] = x2 * cn + x1 * sn;
  }
  {
    float x1 = Ko[p], x2 = Ko[p + 32];
    Ko[p]      = x1 * cn - x2 * sn;
    Ko[p + 32] = x2 * cn + x1 * sn;
  }
}

// ---------------------------------------------------------------------------
// Kernel 3: causal flash attention. Block = 256 threads = 256 q rows;
// one q row per thread, K/V 64-row tiles staged in LDS (broadcast reads).
// Online softmax in chunks of 16 to bound VGPRs.
// ---------------------------------------------------------------------------
__global__ __launch_bounds__(256) void attn(
    const float* __restrict__ Q, const float* __restrict__ Kb,
    const float* __restrict__ Vb, float* __restrict__ Y)
{
  __shared__ float Ks[64 * 64];
  __shared__ float Vs[64 * 64];
  const int tid = threadIdx.x;
  const int bh  = blockIdx.x >> 3;
  const int qt  = 7 - (blockIdx.x & 7);   // heavy q-tiles dispatch first
  const int b   = bh >> 4, h = bh & 15;
  const int qi  = qt * 256 + tid;         // this thread's query row

  const float* qp = Q + ((size_t)bh * T_ + qi) * HD_;
  float qreg[64];
#pragma unroll
  for (int d4 = 0; d4 < 16; ++d4) {
    const float4 w = ((const float4*)qp)[d4];
    qreg[d4*4+0] = w.x; qreg[d4*4+1] = w.y; qreg[d4*4+2] = w.z; qreg[d4*4+3] = w.w;
  }
  float acc[64];
#pragma unroll
  for (int d = 0; d < 64; ++d) acc[d] = 0.f;
  float mmax = -1e30f, lsum = 0.f;

  const int nkt = qt * 4 + 4;             // causal: k-tiles 0..(qt*4+3)
  const float* kbase = Kb + (size_t)bh * T_ * HD_;
  const float* vbase = Vb + (size_t)bh * T_ * HD_;

  for (int kt = 0; kt < nkt; ++kt) {
    __syncthreads();
    {
      const float4* ks = (const float4*)(kbase + (size_t)kt * 64 * HD_);
      const float4* vs = (const float4*)(vbase + (size_t)kt * 64 * HD_);
#pragma unroll
      for (int i = 0; i < 4; ++i) {
        const int gi = i * 256 + tid;     // 0..1023 float4 chunks
        ((float4*)Ks)[gi] = ks[gi];
        ((float4*)Vs)[gi] = vs[gi];
      }
    }
    __syncthreads();

    const int kt0 = kt * 64;
    for (int jc = 0; jc < 64; jc += 16) {
      float s[16];
#pragma unroll
      for (int jj = 0; jj < 16; ++jj) {
        const float* kr = &Ks[(jc + jj) * 64];
        float dot = 0.f;
#pragma unroll
        for (int d = 0; d < 64; ++d) dot += qreg[d] * kr[d];
        s[jj] = (kt0 + jc + jj <= qi) ? dot * 0.125f : -1e30f;
      }
      float cmax = s[0];
#pragma unroll
      for (int jj = 1; jj < 16; ++jj) cmax = fmaxf(cmax, s[jj]);
      const float mnew = fmaxf(mmax, cmax);
      const float rsc  = __expf(mmax - mnew);
      lsum *= rsc;
#pragma unroll
      for (int d = 0; d < 64; ++d) acc[d] *= rsc;
#pragma unroll
      for (int jj = 0; jj < 16; ++jj) {
        const float p = __expf(s[jj] - mnew);
        lsum += p;
        const float* vr = &Vs[(jc + jj) * 64];
#pragma unroll
        for (int d = 0; d < 64; ++d) acc[d] += p * vr[d];
      }
      mmax = mnew;
    }
  }

  const float invl = 1.f / lsum;
  float* yp = Y + ((size_t)b * T_ + qi) * C_ + h * HD_;
#pragma unroll
  for (int d = 0; d < 64; ++d) yp[d] = acc[d] * invl;
}

// ---------------------------------------------------------------------------
// Kernel 4: out = y @ w_proj + b_proj  (same GEMM structure, N=1024)
// ---------------------------------------------------------------------------
__global__ __launch_bounds__(256) void gemm_proj(
    const float* __restrict__ Yb, const float* __restrict__ W,
    const float* __restrict__ bias, float* __restrict__ Out)
{
  __shared__ float As[32][68];
  __shared__ float Bs[32][68];
  const int tid  = threadIdx.x;
  const int row0 = blockIdx.y * 64;
  const int col0 = blockIdx.x * 64;
  const int tx = tid & 15, ty = tid >> 4;
  const int am = tid >> 2, ak = (tid & 3) * 8;
  const int bk = tid >> 3, bn = (tid & 7) * 8;
  float acc[4][4] = {};

  for (int k0 = 0; k0 < C_; k0 += 32) {
    const float4 a0 = *(const float4*)(Yb + (size_t)(row0 + am) * C_ + k0 + ak);
    const float4 a1 = *(const float4*)(Yb + (size_t)(row0 + am) * C_ + k0 + ak + 4);
    const float4 b0 = *(const float4*)(W + (size_t)(k0 + bk) * C_ + col0 + bn);
    const float4 b1 = *(const float4*)(W + (size_t)(k0 + bk) * C_ + col0 + bn + 4);
    As[ak + 0][am] = a0.x; As[ak + 1][am] = a0.y;
    As[ak + 2][am] = a0.z; As[ak + 3][am] = a0.w;
    As[ak + 4][am] = a1.x; As[ak + 5][am] = a1.y;
    As[ak + 6][am] = a1.z; As[ak + 7][am] = a1.w;
    *(float4*)&Bs[bk][bn]     = b0;
    *(float4*)&Bs[bk][bn + 4] = b1;
    __syncthreads();
#pragma unroll
    for (int kk = 0; kk < 32; ++kk) {
      float va0 = As[kk][ty*4+0], va1 = As[kk][ty*4+1],
            va2 = As[kk][ty*4+2], va3 = As[kk][ty*4+3];
      float vb0 = Bs[kk][tx*4+0], vb1 = Bs[kk][tx*4+1],
            vb2 = Bs[kk][tx*4+2], vb3 = Bs[kk][tx*4+3];
      acc[0][0] += va0*vb0; acc[0][1] += va0*vb1; acc[0][2] += va0*vb2; acc[0][3] += va0*vb3;
      acc[1][0] += va1*vb0; acc[1][1] += va1*vb1; acc[1][2] += va1*vb2; acc[1][3] += va1*vb3;
      acc[2][0] += va2*vb0; acc[2][1] += va2*vb1; acc[2][2] += va2*vb2; acc[2][3] += va2*vb3;
      acc[3][0] += va3*vb0; acc[3][1] += va3*vb1; acc[3][2] += va3*vb2; acc[3][3] += va3*vb3;
    }
    __syncthreads();
  }

#pragma unroll
  for (int i = 0; i < 4; ++i) {
    const int r = row0 + ty * 4 + i;
#pragma unroll
    for (int j = 0; j < 4; ++j) {
      const int n = col0 + tx * 4 + j;
      Out[(size_t)r * C_ + n] = acc[i][j] + bias[n];
    }
  }
}

extern "C" void kernel_launch(void* const* d_in, const int* in_sizes, int n_in,
                              void* d_out, int out_size, void* d_ws, size_t ws_size,
                              hipStream_t stream) {
  const float* x      = (const float*)d_in[0];
  const float* w_attn = (const float*)d_in[1];
  const float* b_attn = (const float*)d_in[2];
  const float* w_proj = (const float*)d_in[3];
  const float* b_proj = (const float*)d_in[4];
  float* out = (float*)d_out;

  const size_t elems = (size_t)BT_ * C_;   // 8,388,608
  float* q = (float*)d_ws;
  float* k = q + elems;
  float* v = k + elems;
  float* y = v + elems;                    // total ws use: 128 MiB

  gemm_qkv<<<dim3(N3C / 64, BT_ / 64), 256, 0, stream>>>(x, w_attn, b_attn, q, k, v);
  rope_qk<<<dim3((B_ * NH_ * T_ * 32) / 256), 256, 0, stream>>>(q, k);
  attn<<<dim3(B_ * NH_ * 8), 256, 0, stream>>>(q, k, v, y);
  gemm_proj<<<dim3(C_ / 64, BT_ / 64), 256, 0, stream>>>(y, w_proj, b_proj, out);
}

// Round 3
// 1112.927 us; speedup vs baseline: 2.8135x; 2.8135x over previous
//
#include <hip/hip_runtime.h>

// Problem constants
#define B_  4
#define T_  2048
#define C_  1024
#define NH_ 16
#define HD_ 64
#define BT_ (B_*T_)   // 8192
#define N3C (3*C_)    // 3072

typedef _Float16 f16;
typedef _Float16 half8 __attribute__((ext_vector_type(8)));
typedef _Float16 half4 __attribute__((ext_vector_type(4)));
typedef float f32x4 __attribute__((ext_vector_type(4)));

// ---------------------------------------------------------------------------
// Kernel 1: qkv = x @ w_attn + b_attn, scattered to q/k/v in (B,NH,T,HD) fp32.
// ---------------------------------------------------------------------------
__global__ __launch_bounds__(256) void gemm_qkv(
    const float* __restrict__ X, const float* __restrict__ W,
    const float* __restrict__ bias,
    float* __restrict__ Qo, float* __restrict__ Ko, float* __restrict__ Vo)
{
  __shared__ float As[32][68];
  __shared__ float Bs[32][68];
  const int tid  = threadIdx.x;
  const int row0 = blockIdx.y * 64;
  const int col0 = blockIdx.x * 64;
  const int tx = tid & 15, ty = tid >> 4;
  const int am = tid >> 2, ak = (tid & 3) * 8;
  const int bk = tid >> 3, bn = (tid & 7) * 8;
  float acc[4][4] = {};

  for (int k0 = 0; k0 < C_; k0 += 32) {
    const float4 a0 = *(const float4*)(X + (size_t)(row0 + am) * C_ + k0 + ak);
    const float4 a1 = *(const float4*)(X + (size_t)(row0 + am) * C_ + k0 + ak + 4);
    const float4 b0 = *(const float4*)(W + (size_t)(k0 + bk) * N3C + col0 + bn);
    const float4 b1 = *(const float4*)(W + (size_t)(k0 + bk) * N3C + col0 + bn + 4);
    As[ak + 0][am] = a0.x; As[ak + 1][am] = a0.y;
    As[ak + 2][am] = a0.z; As[ak + 3][am] = a0.w;
    As[ak + 4][am] = a1.x; As[ak + 5][am] = a1.y;
    As[ak + 6][am] = a1.z; As[ak + 7][am] = a1.w;
    *(float4*)&Bs[bk][bn]     = b0;
    *(float4*)&Bs[bk][bn + 4] = b1;
    __syncthreads();
#pragma unroll
    for (int kk = 0; kk < 32; ++kk) {
      float va0 = As[kk][ty*4+0], va1 = As[kk][ty*4+1],
            va2 = As[kk][ty*4+2], va3 = As[kk][ty*4+3];
      float vb0 = Bs[kk][tx*4+0], vb1 = Bs[kk][tx*4+1],
            vb2 = Bs[kk][tx*4+2], vb3 = Bs[kk][tx*4+3];
      acc[0][0] += va0*vb0; acc[0][1] += va0*vb1; acc[0][2] += va0*vb2; acc[0][3] += va0*vb3;
      acc[1][0] += va1*vb0; acc[1][1] += va1*vb1; acc[1][2] += va1*vb2; acc[1][3] += va1*vb3;
      acc[2][0] += va2*vb0; acc[2][1] += va2*vb1; acc[2][2] += va2*vb2; acc[2][3] += va2*vb3;
      acc[3][0] += va3*vb0; acc[3][1] += va3*vb1; acc[3][2] += va3*vb2; acc[3][3] += va3*vb3;
    }
    __syncthreads();
  }

  const int region = col0 >> 10;           // 0=q 1=k 2=v
  const int h      = (col0 & 1023) >> 6;
  float* dst = (region == 0) ? Qo : ((region == 1) ? Ko : Vo);
#pragma unroll
  for (int i = 0; i < 4; ++i) {
    const int r = row0 + ty * 4 + i;
    const int b = r >> 11, t = r & (T_ - 1);
    const size_t base = ((size_t)(b * NH_ + h) * T_ + t) * HD_;
#pragma unroll
    for (int j = 0; j < 4; ++j) {
      const int d = tx * 4 + j;
      dst[base + d] = acc[i][j] + bias[col0 + d];
    }
  }
}

// ---------------------------------------------------------------------------
// Kernel 2: in-place RoPE on q and k.
// ---------------------------------------------------------------------------
__global__ __launch_bounds__(256) void rope_qk(float* __restrict__ Q,
                                               float* __restrict__ Ko)
{
  const int idx = blockIdx.x * 256 + threadIdx.x;
  const int f   = idx & 31;
  const int row = idx >> 5;
  const int t   = row & (T_ - 1);
  const float e   = (float)(2 * f) * (1.0f / 64.0f);
  const float inv = expf(-e * 9.210340371976184f);
  const float ang = (float)t * inv;
  float sn, cn;
  sincosf(ang, &sn, &cn);

  const size_t p = (size_t)row * HD_ + f;
  {
    float x1 = Q[p], x2 = Q[p + 32];
    Q[p]      = x1 * cn - x2 * sn;
    Q[p + 32] = x2 * cn + x1 * sn;
  }
  {
    float x1 = Ko[p], x2 = Ko[p + 32];
    Ko[p]      = x1 * cn - x2 * sn;
    Ko[p + 32] = x2 * cn + x1 * sn;
  }
}

// ---------------------------------------------------------------------------
// Kernel 3: MFMA flash attention.
// Block = 256 threads = 4 waves; block owns 64 q rows (wave w: 16 rows).
// Per 64-key tile: S^T = K·Q^T via mfma_f32_16x16x32_f16 (C-layout cols = q
// = lane&15 -> per-lane softmax, 2 shuffles for cross-quad reduce), then
// P^T (C-layout rows = quad*4+reg) feeds directly as B-operand of
// mfma_f32_16x16x16f16 (k = quad*4+j): O^T = V^T·P^T, V staged transposed.
// ---------------------------------------------------------------------------
__global__ __launch_bounds__(256) void attn_mfma(
    const float* __restrict__ Qg, const float* __restrict__ Kg,
    const float* __restrict__ Vg, float* __restrict__ Y)
{
  __shared__ f16 Ks[64][72];   // [key][hd], stride 144 B (16B-aligned rows)
  __shared__ f16 Vt[64][72];   // [hd][key], transposed V
  const int tid  = threadIdx.x;
  const int qt   = 31 - (blockIdx.x >> 6);   // heavy q-tiles first
  const int bh   = blockIdx.x & 63;
  const int b    = bh >> 4, h = bh & 15;
  const int wave = tid >> 6, lane = tid & 63;
  const int l    = lane & 15, quad = lane >> 4;
  const int qrow = qt * 64 + wave * 16 + l;  // this lane's q (column n = l)

  // Q fragment: B-operand of 16x16x32 (n = l, k = s*32 + quad*8 + j)
  const float* qp = Qg + ((size_t)bh * T_ + qrow) * HD_;
  half8 qf[2];
#pragma unroll
  for (int s = 0; s < 2; ++s) {
    const float4 w0 = *(const float4*)(qp + s * 32 + quad * 8);
    const float4 w1 = *(const float4*)(qp + s * 32 + quad * 8 + 4);
    qf[s][0] = (f16)w0.x; qf[s][1] = (f16)w0.y;
    qf[s][2] = (f16)w0.z; qf[s][3] = (f16)w0.w;
    qf[s][4] = (f16)w1.x; qf[s][5] = (f16)w1.y;
    qf[s][6] = (f16)w1.z; qf[s][7] = (f16)w1.w;
  }

  f32x4 O[4];
#pragma unroll
  for (int mi = 0; mi < 4; ++mi) O[mi] = (f32x4)0.0f;
  float m_run = -1e30f, l_run = 0.f;

  const float* kbase = Kg + (size_t)bh * T_ * HD_;
  const float* vbase = Vg + (size_t)bh * T_ * HD_;

  for (int kt = 0; kt <= qt; ++kt) {
    __syncthreads();
    // Stage 64x64 K (rows) and V (transposed) as f16
#pragma unroll
    for (int i = 0; i < 2; ++i) {
      const int idx = i * 2048 + tid * 8;
      const int r = idx >> 6, c = idx & 63;
      const float* kp = kbase + (size_t)(kt * 64 + r) * HD_ + c;
      const float* vp = vbase + (size_t)(kt * 64 + r) * HD_ + c;
      const float4 k0 = *(const float4*)kp, k1 = *(const float4*)(kp + 4);
      const float4 v0 = *(const float4*)vp, v1 = *(const float4*)(vp + 4);
      half8 hk;
      hk[0] = (f16)k0.x; hk[1] = (f16)k0.y; hk[2] = (f16)k0.z; hk[3] = (f16)k0.w;
      hk[4] = (f16)k1.x; hk[5] = (f16)k1.y; hk[6] = (f16)k1.z; hk[7] = (f16)k1.w;
      *(half8*)&Ks[r][c] = hk;
      Vt[c + 0][r] = (f16)v0.x; Vt[c + 1][r] = (f16)v0.y;
      Vt[c + 2][r] = (f16)v0.z; Vt[c + 3][r] = (f16)v0.w;
      Vt[c + 4][r] = (f16)v1.x; Vt[c + 5][r] = (f16)v1.y;
      Vt[c + 6][r] = (f16)v1.z; Vt[c + 7][r] = (f16)v1.w;
    }
    __syncthreads();

    // S^T = K_tile · Q^T   (M=key 64 -> 4 subtiles, N=q 16, K=hd 64 -> 2 steps)
    f32x4 St[4];
#pragma unroll
    for (int st = 0; st < 4; ++st) {
      f32x4 acc = (f32x4)0.0f;
#pragma unroll
      for (int s = 0; s < 2; ++s) {
        const half8 af = *(const half8*)&Ks[st * 16 + l][s * 32 + quad * 8];
        acc = __builtin_amdgcn_mfma_f32_16x16x32_f16(af, qf[s], acc, 0, 0, 0);
      }
      St[st] = acc;
    }

    // Online softmax. Lane holds S^T[key = st*16+quad*4+r][q = l].
    float p[4][4];
    float cmax = -1e30f;
    const bool diag = (kt == qt);
#pragma unroll
    for (int st = 0; st < 4; ++st)
#pragma unroll
      for (int r = 0; r < 4; ++r) {
        float x = St[st][r] * 0.125f;
        if (diag) {
          const int key = kt * 64 + st * 16 + quad * 4 + r;
          if (key > qrow) x = -1e9f;
        }
        p[st][r] = x;
        cmax = fmaxf(cmax, x);
      }
    cmax = fmaxf(cmax, __shfl_xor(cmax, 16));
    cmax = fmaxf(cmax, __shfl_xor(cmax, 32));
    const float mnew  = fmaxf(m_run, cmax);
    const float alpha = __expf(m_run - mnew);
    float psum = 0.f;
#pragma unroll
    for (int st = 0; st < 4; ++st)
#pragma unroll
      for (int r = 0; r < 4; ++r) {
        const float ev = __expf(p[st][r] - mnew);
        p[st][r] = ev;
        psum += ev;
      }
    psum += __shfl_xor(psum, 16);
    psum += __shfl_xor(psum, 32);
    l_run = l_run * alpha + psum;
    m_run = mnew;

    half4 pf[4];
#pragma unroll
    for (int st = 0; st < 4; ++st) {
      pf[st][0] = (f16)p[st][0]; pf[st][1] = (f16)p[st][1];
      pf[st][2] = (f16)p[st][2]; pf[st][3] = (f16)p[st][3];
      O[st] *= alpha;
    }

    // O^T += V^T · P^T  (M=hd 64 -> 4 subtiles, N=q 16, K=key 64 -> 4 steps)
#pragma unroll
    for (int mi = 0; mi < 4; ++mi) {
#pragma unroll
      for (int ki = 0; ki < 4; ++ki) {
        const half4 vf = *(const half4*)&Vt[mi * 16 + l][ki * 16 + quad * 4];
        O[mi] = __builtin_amdgcn_mfma_f32_16x16x16f16(vf, pf[ki], O[mi], 0, 0, 0);
      }
    }
  }

  // Epilogue: lane holds O^T[hd = mi*16+quad*4+r][q = l]; write float4s.
  const float inv = 1.0f / l_run;
  float* yp = Y + ((size_t)(b * T_) + qrow) * C_ + h * 64;
#pragma unroll
  for (int mi = 0; mi < 4; ++mi) {
    float4 o;
    o.x = O[mi][0] * inv; o.y = O[mi][1] * inv;
    o.z = O[mi][2] * inv; o.w = O[mi][3] * inv;
    *(float4*)(yp + mi * 16 + quad * 4) = o;
  }
}

// ---------------------------------------------------------------------------
// Kernel 4: out = y @ w_proj + b_proj
// ---------------------------------------------------------------------------
__global__ __launch_bounds__(256) void gemm_proj(
    const float* __restrict__ Yb, const float* __restrict__ W,
    const float* __restrict__ bias, float* __restrict__ Out)
{
  __shared__ float As[32][68];
  __shared__ float Bs[32][68];
  const int tid  = threadIdx.x;
  const int row0 = blockIdx.y * 64;
  const int col0 = blockIdx.x * 64;
  const int tx = tid & 15, ty = tid >> 4;
  const int am = tid >> 2, ak = (tid & 3) * 8;
  const int bk = tid >> 3, bn = (tid & 7) * 8;
  float acc[4][4] = {};

  for (int k0 = 0; k0 < C_; k0 += 32) {
    const float4 a0 = *(const float4*)(Yb + (size_t)(row0 + am) * C_ + k0 + ak);
    const float4 a1 = *(const float4*)(Yb + (size_t)(row0 + am) * C_ + k0 + ak + 4);
    const float4 b0 = *(const float4*)(W + (size_t)(k0 + bk) * C_ + col0 + bn);
    const float4 b1 = *(const float4*)(W + (size_t)(k0 + bk) * C_ + col0 + bn + 4);
    As[ak + 0][am] = a0.x; As[ak + 1][am] = a0.y;
    As[ak + 2][am] = a0.z; As[ak + 3][am] = a0.w;
    As[ak + 4][am] = a1.x; As[ak + 5][am] = a1.y;
    As[ak + 6][am] = a1.z; As[ak + 7][am] = a1.w;
    *(float4*)&Bs[bk][bn]     = b0;
    *(float4*)&Bs[bk][bn + 4] = b1;
    __syncthreads();
#pragma unroll
    for (int kk = 0; kk < 32; ++kk) {
      float va0 = As[kk][ty*4+0], va1 = As[kk][ty*4+1],
            va2 = As[kk][ty*4+2], va3 = As[kk][ty*4+3];
      float vb0 = Bs[kk][tx*4+0], vb1 = Bs[kk][tx*4+1],
            vb2 = Bs[kk][tx*4+2], vb3 = Bs[kk][tx*4+3];
      acc[0][0] += va0*vb0; acc[0][1] += va0*vb1; acc[0][2] += va0*vb2; acc[0][3] += va0*vb3;
      acc[1][0] += va1*vb0; acc[1][1] += va1*vb1; acc[1][2] += va1*vb2; acc[1][3] += va1*vb3;
      acc[2][0] += va2*vb0; acc[2][1] += va2*vb1; acc[2][2] += va2*vb2; acc[2][3] += va2*vb3;
      acc[3][0] += va3*vb0; acc[3][1] += va3*vb1; acc[3][2] += va3*vb2; acc[3][3] += va3*vb3;
    }
    __syncthreads();
  }

#pragma unroll
  for (int i = 0; i < 4; ++i) {
    const int r = row0 + ty * 4 + i;
#pragma unroll
    for (int j = 0; j < 4; ++j) {
      const int n = col0 + tx * 4 + j;
      Out[(size_t)r * C_ + n] = acc[i][j] + bias[n];
    }
  }
}

extern "C" void kernel_launch(void* const* d_in, const int* in_sizes, int n_in,
                              void* d_out, int out_size, void* d_ws, size_t ws_size,
                              hipStream_t stream) {
  const float* x      = (const float*)d_in[0];
  const float* w_attn = (const float*)d_in[1];
  const float* b_attn = (const float*)d_in[2];
  const float* w_proj = (const float*)d_in[3];
  const float* b_proj = (const float*)d_in[4];
  float* out = (float*)d_out;

  const size_t elems = (size_t)BT_ * C_;
  float* q = (float*)d_ws;
  float* k = q + elems;
  float* v = k + elems;
  float* y = v + elems;

  gemm_qkv<<<dim3(N3C / 64, BT_ / 64), 256, 0, stream>>>(x, w_attn, b_attn, q, k, v);
  rope_qk<<<dim3((B_ * NH_ * T_ * 32) / 256), 256, 0, stream>>>(q, k);
  attn_mfma<<<dim3(32 * 64), 256, 0, stream>>>(q, k, v, y);
  gemm_proj<<<dim3(C_ / 64, BT_ / 64), 256, 0, stream>>>(y, w_proj, b_proj, out);
}

// Round 4
// 339.716 us; speedup vs baseline: 9.2172x; 3.2760x over previous
//
#include <hip/hip_runtime.h>

// Problem constants
#define B_  4
#define T_  2048
#define C_  1024
#define NH_ 16
#define HD_ 64
#define BT_ (B_*T_)   // 8192
#define N3C (3*C_)    // 3072

typedef _Float16 f16;
typedef _Float16 half8 __attribute__((ext_vector_type(8)));
typedef _Float16 half4 __attribute__((ext_vector_type(4)));
typedef float f32x4 __attribute__((ext_vector_type(4)));

// ---------------------------------------------------------------------------
// Pre-pass A: x (fp32 row-major) -> x16 (f16 row-major). 8 elems/thread.
// ---------------------------------------------------------------------------
__global__ __launch_bounds__(256) void cvt_x(const float* __restrict__ X,
                                             f16* __restrict__ X16)
{
  const int i = blockIdx.x * 256 + threadIdx.x;   // i < BT_*C_/8
  const float4 a = ((const float4*)X)[i * 2];
  const float4 b = ((const float4*)X)[i * 2 + 1];
  half8 h;
  h[0] = (f16)a.x; h[1] = (f16)a.y; h[2] = (f16)a.z; h[3] = (f16)a.w;
  h[4] = (f16)b.x; h[5] = (f16)b.y; h[6] = (f16)b.z; h[7] = (f16)b.w;
  ((half8*)X16)[i] = h;
}

// ---------------------------------------------------------------------------
// Pre-pass B: W (K x N fp32) -> Wt (N x K f16). 64x64 LDS tiles.
// ---------------------------------------------------------------------------
__global__ __launch_bounds__(256) void cvt_transpose(
    const float* __restrict__ W, f16* __restrict__ Wt, int K, int N)
{
  __shared__ float Ls[64][65];
  const int tid = threadIdx.x;
  const int n0 = blockIdx.x * 64, k0 = blockIdx.y * 64;
#pragma unroll
  for (int j = 0; j < 4; ++j) {
    const int idx = j * 256 + tid;          // 1024 float4 slots
    const int r = idx >> 4, c = (idx & 15) * 4;
    const float4 w = *(const float4*)(W + (size_t)(k0 + r) * N + n0 + c);
    Ls[r][c + 0] = w.x; Ls[r][c + 1] = w.y; Ls[r][c + 2] = w.z; Ls[r][c + 3] = w.w;
  }
  __syncthreads();
#pragma unroll
  for (int j = 0; j < 2; ++j) {
    const int idx = j * 256 + tid;          // 512 half8 slots
    const int r = idx >> 3, c = (idx & 7) * 8;   // r = n row, c = k chunk
    half8 h;
#pragma unroll
    for (int u = 0; u < 8; ++u) h[u] = (f16)Ls[c + u][r];
    *(half8*)(Wt + (size_t)(n0 + r) * K + k0 + c) = h;
  }
}

// ---------------------------------------------------------------------------
// Kernel 1: qkv = x16 @ Wt_attn^T + b_attn -> q/k/v f16 (B,NH,T,HD).
// MFMA 128x128 tile, BK=32, 4 waves (2x2), 16x16x32_f16, reg-prefetch.
// LDS rows padded to 40 f16 (80 B) -> 2-way (free) bank pattern on b128 reads.
// ---------------------------------------------------------------------------
__global__ __launch_bounds__(256) void gemm_qkv(
    const f16* __restrict__ A, const f16* __restrict__ Bt,
    const float* __restrict__ bias,
    f16* __restrict__ Qo, f16* __restrict__ Ko, f16* __restrict__ Vo)
{
  __shared__ f16 As[128][40];
  __shared__ f16 Bs[128][40];
  const int tid  = threadIdx.x;
  const int row0 = blockIdx.y * 128;
  const int col0 = blockIdx.x * 128;
  const int wave = tid >> 6, lane = tid & 63;
  const int l = lane & 15, quad = lane >> 4;
  const int wm = wave >> 1, wn = wave & 1;
  const int sr = tid >> 2, sc = (tid & 3) * 8;   // staging: row sr(+64j), k sc..sc+7

  f32x4 acc[4][4];
#pragma unroll
  for (int mi = 0; mi < 4; ++mi)
#pragma unroll
    for (int ni = 0; ni < 4; ++ni) acc[mi][ni] = (f32x4)0.0f;

  half8 ra[2], rb[2];
#pragma unroll
  for (int j = 0; j < 2; ++j) {
    ra[j] = *(const half8*)(A  + (size_t)(row0 + j * 64 + sr) * C_ + sc);
    rb[j] = *(const half8*)(Bt + (size_t)(col0 + j * 64 + sr) * C_ + sc);
  }

  for (int k0 = 0; k0 < C_; k0 += 32) {
    __syncthreads();
#pragma unroll
    for (int j = 0; j < 2; ++j) {
      *(half8*)&As[j * 64 + sr][sc] = ra[j];
      *(half8*)&Bs[j * 64 + sr][sc] = rb[j];
    }
    __syncthreads();
    if (k0 + 32 < C_) {
#pragma unroll
      for (int j = 0; j < 2; ++j) {
        ra[j] = *(const half8*)(A  + (size_t)(row0 + j * 64 + sr) * C_ + k0 + 32 + sc);
        rb[j] = *(const half8*)(Bt + (size_t)(col0 + j * 64 + sr) * C_ + k0 + 32 + sc);
      }
    }
    half8 af[4], bf[4];
#pragma unroll
    for (int mi = 0; mi < 4; ++mi)
      af[mi] = *(const half8*)&As[wm * 64 + mi * 16 + l][quad * 8];
#pragma unroll
    for (int ni = 0; ni < 4; ++ni)
      bf[ni] = *(const half8*)&Bs[wn * 64 + ni * 16 + l][quad * 8];
#pragma unroll
    for (int mi = 0; mi < 4; ++mi)
#pragma unroll
      for (int ni = 0; ni < 4; ++ni)
        acc[mi][ni] = __builtin_amdgcn_mfma_f32_16x16x32_f16(af[mi], bf[ni], acc[mi][ni], 0, 0, 0);
  }

  // Epilogue: C[m][n], m row = quad*4+reg, n col = l (verified layout).
  const int region = col0 >> 10;           // 0=q 1=k 2=v
  f16* dst = (region == 0) ? Qo : ((region == 1) ? Ko : Vo);
  const int colw = col0 + wn * 64;         // wave's 64-col base (one head)
  const int h = (colw & 1023) >> 6;
#pragma unroll
  for (int mi = 0; mi < 4; ++mi) {
#pragma unroll
    for (int ni = 0; ni < 4; ++ni) {
#pragma unroll
      for (int r = 0; r < 4; ++r) {
        const int gm = row0 + wm * 64 + mi * 16 + quad * 4 + r;
        const int b = gm >> 11, t = gm & (T_ - 1);
        const int d = ni * 16 + l;
        const float val = acc[mi][ni][r] + bias[colw + d];
        dst[((size_t)(b * NH_ + h) * T_ + t) * HD_ + d] = (f16)val;
      }
    }
  }
}

// ---------------------------------------------------------------------------
// Kernel 2: in-place RoPE on q and k (f16).
// ---------------------------------------------------------------------------
__global__ __launch_bounds__(256) void rope_qk(f16* __restrict__ Q,
                                               f16* __restrict__ Ko)
{
  const int idx = blockIdx.x * 256 + threadIdx.x;
  const int f   = idx & 31;
  const int row = idx >> 5;
  const int t   = row & (T_ - 1);
  const float e   = (float)(2 * f) * (1.0f / 64.0f);
  const float inv = expf(-e * 9.210340371976184f);
  const float ang = (float)t * inv;
  float sn, cn;
  sincosf(ang, &sn, &cn);

  const size_t p = (size_t)row * HD_ + f;
  {
    float x1 = (float)Q[p], x2 = (float)Q[p + 32];
    Q[p]      = (f16)(x1 * cn - x2 * sn);
    Q[p + 32] = (f16)(x2 * cn + x1 * sn);
  }
  {
    float x1 = (float)Ko[p], x2 = (float)Ko[p + 32];
    Ko[p]      = (f16)(x1 * cn - x2 * sn);
    Ko[p + 32] = (f16)(x2 * cn + x1 * sn);
  }
}

// ---------------------------------------------------------------------------
// Kernel 3: MFMA flash attention (f16 I/O). Same verified structure as R3.
// ---------------------------------------------------------------------------
__global__ __launch_bounds__(256) void attn_mfma(
    const f16* __restrict__ Qg, const f16* __restrict__ Kg,
    const f16* __restrict__ Vg, f16* __restrict__ Y)
{
  __shared__ f16 Ks[64][72];
  __shared__ f16 Vt[64][72];
  const int tid  = threadIdx.x;
  const int qt   = 31 - (blockIdx.x >> 6);
  const int bh   = blockIdx.x & 63;
  const int b    = bh >> 4, h = bh & 15;
  const int wave = tid >> 6, lane = tid & 63;
  const int l    = lane & 15, quad = lane >> 4;
  const int qrow = qt * 64 + wave * 16 + l;

  const f16* qp = Qg + ((size_t)bh * T_ + qrow) * HD_;
  half8 qf[2];
#pragma unroll
  for (int s = 0; s < 2; ++s)
    qf[s] = *(const half8*)(qp + s * 32 + quad * 8);

  f32x4 O[4];
#pragma unroll
  for (int mi = 0; mi < 4; ++mi) O[mi] = (f32x4)0.0f;
  float m_run = -1e30f, l_run = 0.f;

  const f16* kbase = Kg + (size_t)bh * T_ * HD_;
  const f16* vbase = Vg + (size_t)bh * T_ * HD_;

  for (int kt = 0; kt <= qt; ++kt) {
    __syncthreads();
#pragma unroll
    for (int i = 0; i < 2; ++i) {
      const int idx = i * 2048 + tid * 8;
      const int r = idx >> 6, c = idx & 63;
      const half8 hk = *(const half8*)(kbase + (size_t)(kt * 64 + r) * HD_ + c);
      const half8 hv = *(const half8*)(vbase + (size_t)(kt * 64 + r) * HD_ + c);
      *(half8*)&Ks[r][c] = hk;
#pragma unroll
      for (int u = 0; u < 8; ++u) Vt[c + u][r] = hv[u];
    }
    __syncthreads();

    f32x4 St[4];
#pragma unroll
    for (int st = 0; st < 4; ++st) {
      f32x4 s_acc = (f32x4)0.0f;
#pragma unroll
      for (int s = 0; s < 2; ++s) {
        const half8 af = *(const half8*)&Ks[st * 16 + l][s * 32 + quad * 8];
        s_acc = __builtin_amdgcn_mfma_f32_16x16x32_f16(af, qf[s], s_acc, 0, 0, 0);
      }
      St[st] = s_acc;
    }

    float p[4][4];
    float cmax = -1e30f;
    const bool diag = (kt == qt);
#pragma unroll
    for (int st = 0; st < 4; ++st)
#pragma unroll
      for (int r = 0; r < 4; ++r) {
        float x = St[st][r] * 0.125f;
        if (diag) {
          const int key = kt * 64 + st * 16 + quad * 4 + r;
          if (key > qrow) x = -1e9f;
        }
        p[st][r] = x;
        cmax = fmaxf(cmax, x);
      }
    cmax = fmaxf(cmax, __shfl_xor(cmax, 16));
    cmax = fmaxf(cmax, __shfl_xor(cmax, 32));
    const float mnew  = fmaxf(m_run, cmax);
    const float alpha = __expf(m_run - mnew);
    float psum = 0.f;
#pragma unroll
    for (int st = 0; st < 4; ++st)
#pragma unroll
      for (int r = 0; r < 4; ++r) {
        const float ev = __expf(p[st][r] - mnew);
        p[st][r] = ev;
        psum += ev;
      }
    psum += __shfl_xor(psum, 16);
    psum += __shfl_xor(psum, 32);
    l_run = l_run * alpha + psum;
    m_run = mnew;

    half4 pf[4];
#pragma unroll
    for (int st = 0; st < 4; ++st) {
      pf[st][0] = (f16)p[st][0]; pf[st][1] = (f16)p[st][1];
      pf[st][2] = (f16)p[st][2]; pf[st][3] = (f16)p[st][3];
      O[st] *= alpha;
    }

#pragma unroll
    for (int mi = 0; mi < 4; ++mi) {
#pragma unroll
      for (int ki = 0; ki < 4; ++ki) {
        const half4 vf = *(const half4*)&Vt[mi * 16 + l][ki * 16 + quad * 4];
        O[mi] = __builtin_amdgcn_mfma_f32_16x16x16f16(vf, pf[ki], O[mi], 0, 0, 0);
      }
    }
  }

  const float inv = 1.0f / l_run;
  f16* yp = Y + ((size_t)(b * T_) + qrow) * C_ + h * 64;
#pragma unroll
  for (int mi = 0; mi < 4; ++mi) {
    half4 o;
    o[0] = (f16)(O[mi][0] * inv); o[1] = (f16)(O[mi][1] * inv);
    o[2] = (f16)(O[mi][2] * inv); o[3] = (f16)(O[mi][3] * inv);
    *(half4*)(yp + mi * 16 + quad * 4) = o;
  }
}

// ---------------------------------------------------------------------------
// Kernel 4: out = y @ w_proj + b_proj (fp32 out). Same MFMA structure.
// ---------------------------------------------------------------------------
__global__ __launch_bounds__(256) void gemm_proj(
    const f16* __restrict__ A, const f16* __restrict__ Bt,
    const float* __restrict__ bias, float* __restrict__ Out)
{
  __shared__ f16 As[128][40];
  __shared__ f16 Bs[128][40];
  const int tid  = threadIdx.x;
  const int row0 = blockIdx.y * 128;
  const int col0 = blockIdx.x * 128;
  const int wave = tid >> 6, lane = tid & 63;
  const int l = lane & 15, quad = lane >> 4;
  const int wm = wave >> 1, wn = wave & 1;
  const int sr = tid >> 2, sc = (tid & 3) * 8;

  f32x4 acc[4][4];
#pragma unroll
  for (int mi = 0; mi < 4; ++mi)
#pragma unroll
    for (int ni = 0; ni < 4; ++ni) acc[mi][ni] = (f32x4)0.0f;

  half8 ra[2], rb[2];
#pragma unroll
  for (int j = 0; j < 2; ++j) {
    ra[j] = *(const half8*)(A  + (size_t)(row0 + j * 64 + sr) * C_ + sc);
    rb[j] = *(const half8*)(Bt + (size_t)(col0 + j * 64 + sr) * C_ + sc);
  }

  for (int k0 = 0; k0 < C_; k0 += 32) {
    __syncthreads();
#pragma unroll
    for (int j = 0; j < 2; ++j) {
      *(half8*)&As[j * 64 + sr][sc] = ra[j];
      *(half8*)&Bs[j * 64 + sr][sc] = rb[j];
    }
    __syncthreads();
    if (k0 + 32 < C_) {
#pragma unroll
      for (int j = 0; j < 2; ++j) {
        ra[j] = *(const half8*)(A  + (size_t)(row0 + j * 64 + sr) * C_ + k0 + 32 + sc);
        rb[j] = *(const half8*)(Bt + (size_t)(col0 + j * 64 + sr) * C_ + k0 + 32 + sc);
      }
    }
    half8 af[4], bf[4];
#pragma unroll
    for (int mi = 0; mi < 4; ++mi)
      af[mi] = *(const half8*)&As[wm * 64 + mi * 16 + l][quad * 8];
#pragma unroll
    for (int ni = 0; ni < 4; ++ni)
      bf[ni] = *(const half8*)&Bs[wn * 64 + ni * 16 + l][quad * 8];
#pragma unroll
    for (int mi = 0; mi < 4; ++mi)
#pragma unroll
      for (int ni = 0; ni < 4; ++ni)
        acc[mi][ni] = __builtin_amdgcn_mfma_f32_16x16x32_f16(af[mi], bf[ni], acc[mi][ni], 0, 0, 0);
  }

#pragma unroll
  for (int mi = 0; mi < 4; ++mi) {
#pragma unroll
    for (int ni = 0; ni < 4; ++ni) {
#pragma unroll
      for (int r = 0; r < 4; ++r) {
        const int gm = row0 + wm * 64 + mi * 16 + quad * 4 + r;
        const int n  = col0 + wn * 64 + ni * 16 + l;
        Out[(size_t)gm * C_ + n] = acc[mi][ni][r] + bias[n];
      }
    }
  }
}

extern "C" void kernel_launch(void* const* d_in, const int* in_sizes, int n_in,
                              void* d_out, int out_size, void* d_ws, size_t ws_size,
                              hipStream_t stream) {
  const float* x      = (const float*)d_in[0];
  const float* w_attn = (const float*)d_in[1];
  const float* b_attn = (const float*)d_in[2];
  const float* w_proj = (const float*)d_in[3];
  const float* b_proj = (const float*)d_in[4];
  float* out = (float*)d_out;

  const size_t elems = (size_t)BT_ * C_;       // 8,388,608
  f16* x16 = (f16*)d_ws;
  f16* wta = x16 + elems;                      // 3072*1024
  f16* wtp = wta + (size_t)N3C * C_;           // 1024*1024
  f16* q   = wtp + (size_t)C_ * C_;
  f16* k   = q + elems;
  f16* v   = k + elems;
  f16* y   = v + elems;                        // total ~92.3 MB

  cvt_x<<<dim3(elems / 8 / 256), 256, 0, stream>>>(x, x16);
  cvt_transpose<<<dim3(N3C / 64, C_ / 64), 256, 0, stream>>>(w_attn, wta, C_, N3C);
  cvt_transpose<<<dim3(C_ / 64, C_ / 64), 256, 0, stream>>>(w_proj, wtp, C_, C_);
  gemm_qkv<<<dim3(N3C / 128, BT_ / 128), 256, 0, stream>>>(x16, wta, b_attn, q, k, v);
  rope_qk<<<dim3((B_ * NH_ * T_ * 32) / 256), 256, 0, stream>>>(q, k);
  attn_mfma<<<dim3(32 * 64), 256, 0, stream>>>(q, k, v, y);
  gemm_proj<<<dim3(C_ / 128, BT_ / 128), 256, 0, stream>>>(y, wtp, b_proj, out);
}

// Round 5
// 290.015 us; speedup vs baseline: 10.7968x; 1.1714x over previous
//
#include <hip/hip_runtime.h>

// Problem constants
#define B_  4
#define T_  2048
#define C_  1024
#define NH_ 16
#define HD_ 64
#define BT_ (B_*T_)   // 8192
#define N3C (3*C_)    // 3072

typedef _Float16 f16;
typedef _Float16 half8 __attribute__((ext_vector_type(8)));
typedef _Float16 half4 __attribute__((ext_vector_type(4)));
typedef float f32x4 __attribute__((ext_vector_type(4)));

// Async global->LDS, 16 B per lane. LDS dest must be lane-linear (base + lane*16).
__device__ __forceinline__ void gld16(const f16* g, f16* l) {
  __builtin_amdgcn_global_load_lds(
      (const __attribute__((address_space(1))) unsigned int*)g,
      (__attribute__((address_space(3))) unsigned int*)l, 16, 0, 0);
}

// ---------------------------------------------------------------------------
// Pre-pass A: x (fp32) -> x16 (f16).
// ---------------------------------------------------------------------------
__global__ __launch_bounds__(256) void cvt_x(const float* __restrict__ X,
                                             f16* __restrict__ X16)
{
  const int i = blockIdx.x * 256 + threadIdx.x;
  const float4 a = ((const float4*)X)[i * 2];
  const float4 b = ((const float4*)X)[i * 2 + 1];
  half8 h;
  h[0] = (f16)a.x; h[1] = (f16)a.y; h[2] = (f16)a.z; h[3] = (f16)a.w;
  h[4] = (f16)b.x; h[5] = (f16)b.y; h[6] = (f16)b.z; h[7] = (f16)b.w;
  ((half8*)X16)[i] = h;
}

// ---------------------------------------------------------------------------
// Pre-pass B: W (K x N fp32) -> Wt (N x K f16).
// ---------------------------------------------------------------------------
__global__ __launch_bounds__(256) void cvt_transpose(
    const float* __restrict__ W, f16* __restrict__ Wt, int K, int N)
{
  __shared__ float Ls[64][65];
  const int tid = threadIdx.x;
  const int n0 = blockIdx.x * 64, k0 = blockIdx.y * 64;
#pragma unroll
  for (int j = 0; j < 4; ++j) {
    const int idx = j * 256 + tid;
    const int r = idx >> 4, c = (idx & 15) * 4;
    const float4 w = *(const float4*)(W + (size_t)(k0 + r) * N + n0 + c);
    Ls[r][c + 0] = w.x; Ls[r][c + 1] = w.y; Ls[r][c + 2] = w.z; Ls[r][c + 3] = w.w;
  }
  __syncthreads();
#pragma unroll
  for (int j = 0; j < 2; ++j) {
    const int idx = j * 256 + tid;
    const int r = idx >> 3, c = (idx & 7) * 8;
    half8 h;
#pragma unroll
    for (int u = 0; u < 8; ++u) h[u] = (f16)Ls[c + u][r];
    *(half8*)(Wt + (size_t)(n0 + r) * K + k0 + c) = h;
  }
}

// ---------------------------------------------------------------------------
// Kernel 1: qkv GEMM, m97-style: global_load_lds(16B) staging, unpadded
// [128][32] f16 LDS tiles, 2-barrier K-loop, 16x16x32_f16 MFMA.
// q/k -> (B,NH,T,HD) row-major; v -> Vt_g[bh][hd][t] transposed (half4 stores).
// ---------------------------------------------------------------------------
__global__ __launch_bounds__(256) void gemm_qkv(
    const f16* __restrict__ A, const f16* __restrict__ Bt,
    const float* __restrict__ bias,
    f16* __restrict__ Qo, f16* __restrict__ Ko, f16* __restrict__ Vt_g)
{
  __shared__ f16 As[128 * 32];
  __shared__ f16 Bs[128 * 32];
  const int tid  = threadIdx.x;
  const int row0 = blockIdx.y * 128;
  const int col0 = blockIdx.x * 128;
  const int wave = tid >> 6, lane = tid & 63;
  const int l = lane & 15, quad = lane >> 4;
  const int wm = wave >> 1, wn = wave & 1;
  const int sr = tid >> 2, sc = (tid & 3) * 8;   // lane-linear: lds idx = p*2048 + tid*8

  f32x4 acc[4][4];
#pragma unroll
  for (int mi = 0; mi < 4; ++mi)
#pragma unroll
    for (int ni = 0; ni < 4; ++ni) acc[mi][ni] = (f32x4)0.0f;

  for (int k0 = 0; k0 < C_; k0 += 32) {
    __syncthreads();
#pragma unroll
    for (int p = 0; p < 2; ++p) {
      gld16(A  + (size_t)(row0 + p * 64 + sr) * C_ + k0 + sc, &As[p * 2048 + tid * 8]);
      gld16(Bt + (size_t)(col0 + p * 64 + sr) * C_ + k0 + sc, &Bs[p * 2048 + tid * 8]);
    }
    __syncthreads();   // compiler drains vmcnt before s_barrier

    half8 af[4], bf[4];
#pragma unroll
    for (int mi = 0; mi < 4; ++mi)
      af[mi] = *(const half8*)&As[(wm * 64 + mi * 16 + l) * 32 + quad * 8];
#pragma unroll
    for (int ni = 0; ni < 4; ++ni)
      bf[ni] = *(const half8*)&Bs[(wn * 64 + ni * 16 + l) * 32 + quad * 8];
#pragma unroll
    for (int mi = 0; mi < 4; ++mi)
#pragma unroll
      for (int ni = 0; ni < 4; ++ni)
        acc[mi][ni] = __builtin_amdgcn_mfma_f32_16x16x32_f16(af[mi], bf[ni], acc[mi][ni], 0, 0, 0);
  }

  const int region = col0 >> 10;           // 0=q 1=k 2=v
  const int colw = col0 + wn * 64;
  const int h = (colw & 1023) >> 6;
  if (region < 2) {
    f16* dst = (region == 0) ? Qo : Ko;
#pragma unroll
    for (int mi = 0; mi < 4; ++mi) {
#pragma unroll
      for (int ni = 0; ni < 4; ++ni) {
#pragma unroll
        for (int r = 0; r < 4; ++r) {
          const int gm = row0 + wm * 64 + mi * 16 + quad * 4 + r;
          const int b = gm >> 11, t = gm & (T_ - 1);
          const int d = ni * 16 + l;
          const float val = acc[mi][ni][r] + bias[colw + d];
          dst[((size_t)(b * NH_ + h) * T_ + t) * HD_ + d] = (f16)val;
        }
      }
    }
  } else {
    // V transposed: Vt_g[(bh*64 + d) * T + t], vectorized over r (t-contiguous)
#pragma unroll
    for (int mi = 0; mi < 4; ++mi) {
      const int t0 = row0 + wm * 64 + mi * 16 + quad * 4;   // t = t0 + r (same b for all r)
      const int b = t0 >> 11, t = t0 & (T_ - 1);
#pragma unroll
      for (int ni = 0; ni < 4; ++ni) {
        const int d = ni * 16 + l;
        const float bs = bias[colw + d];
        half4 o;
#pragma unroll
        for (int r = 0; r < 4; ++r) o[r] = (f16)(acc[mi][ni][r] + bs);
        *(half4*)(Vt_g + ((size_t)((b * NH_ + h) * HD_ + d)) * T_ + t) = o;
      }
    }
  }
}

// ---------------------------------------------------------------------------
// Kernel 2: in-place RoPE on q and k (f16).
// ---------------------------------------------------------------------------
__global__ __launch_bounds__(256) void rope_qk(f16* __restrict__ Q,
                                               f16* __restrict__ Ko)
{
  const int idx = blockIdx.x * 256 + threadIdx.x;
  const int f   = idx & 31;
  const int row = idx >> 5;
  const int t   = row & (T_ - 1);
  const float e   = (float)(2 * f) * (1.0f / 64.0f);
  const float inv = expf(-e * 9.210340371976184f);
  const float ang = (float)t * inv;
  float sn, cn;
  sincosf(ang, &sn, &cn);

  const size_t p = (size_t)row * HD_ + f;
  {
    float x1 = (float)Q[p], x2 = (float)Q[p + 32];
    Q[p]      = (f16)(x1 * cn - x2 * sn);
    Q[p + 32] = (f16)(x2 * cn + x1 * sn);
  }
  {
    float x1 = (float)Ko[p], x2 = (float)Ko[p + 32];
    Ko[p]      = (f16)(x1 * cn - x2 * sn);
    Ko[p + 32] = (f16)(x2 * cn + x1 * sn);
  }
}

// ---------------------------------------------------------------------------
// Kernel 3: MFMA flash attention. V^T comes pre-transposed from global.
// LDS: unpadded 64x64 tiles with XOR chunk swizzle (chunk' = chunk ^ (row&7))
// -> staging writes, QK b128 reads, PV b64 reads all bank-balanced.
// ---------------------------------------------------------------------------
__global__ __launch_bounds__(256) void attn_mfma(
    const f16* __restrict__ Qg, const f16* __restrict__ Kg,
    const f16* __restrict__ Vt_g, f16* __restrict__ Y)
{
  __shared__ f16 Ks[64 * 64];   // [key][hd], swizzled
  __shared__ f16 Vt[64 * 64];   // [hd][key], swizzled
  const int tid  = threadIdx.x;
  const int qt   = 31 - (blockIdx.x >> 6);
  const int bh   = blockIdx.x & 63;
  const int b    = bh >> 4, h = bh & 15;
  const int wave = tid >> 6, lane = tid & 63;
  const int l    = lane & 15, quad = lane >> 4;
  const int qrow = qt * 64 + wave * 16 + l;

  const f16* qp = Qg + ((size_t)bh * T_ + qrow) * HD_;
  half8 qf[2];
#pragma unroll
  for (int s = 0; s < 2; ++s)
    qf[s] = *(const half8*)(qp + s * 32 + quad * 8);

  f32x4 O[4];
#pragma unroll
  for (int mi = 0; mi < 4; ++mi) O[mi] = (f32x4)0.0f;
  float m_run = -1e30f, l_run = 0.f;

  const f16* kbase  = Kg   + (size_t)bh * T_ * HD_;
  const f16* vtbase = Vt_g + (size_t)bh * HD_ * T_;
  const int lq7 = l & 7;

  for (int kt = 0; kt <= qt; ++kt) {
    __syncthreads();
    // Stage: thread -> row r = i*32 + tid>>3, chunk c = tid&7 (half8 each)
#pragma unroll
    for (int i = 0; i < 2; ++i) {
      const int r = i * 32 + (tid >> 3);
      const int c = tid & 7;
      const int cs = ((c ^ (r & 7)) << 3);
      const half8 hk = *(const half8*)(kbase + (size_t)(kt * 64 + r) * HD_ + c * 8);
      *(half8*)&Ks[r * 64 + cs] = hk;
      const half8 hv = *(const half8*)(vtbase + (size_t)r * T_ + kt * 64 + c * 8);
      *(half8*)&Vt[r * 64 + cs] = hv;
    }
    __syncthreads();

    // S^T = K · Q^T
    f32x4 St[4];
#pragma unroll
    for (int st = 0; st < 4; ++st) {
      f32x4 s_acc = (f32x4)0.0f;
#pragma unroll
      for (int s = 0; s < 2; ++s) {
        const int row = st * 16 + l;
        const half8 af = *(const half8*)&Ks[row * 64 + ((((s << 2) | quad) ^ lq7) << 3)];
        s_acc = __builtin_amdgcn_mfma_f32_16x16x32_f16(af, qf[s], s_acc, 0, 0, 0);
      }
      St[st] = s_acc;
    }

    // Online softmax (lane holds S^T[key = st*16+quad*4+r][q = l])
    float p[4][4];
    float cmax = -1e30f;
    const bool diag = (kt == qt);
#pragma unroll
    for (int st = 0; st < 4; ++st)
#pragma unroll
      for (int r = 0; r < 4; ++r) {
        float x = St[st][r] * 0.125f;
        if (diag) {
          const int key = kt * 64 + st * 16 + quad * 4 + r;
          if (key > qrow) x = -1e9f;
        }
        p[st][r] = x;
        cmax = fmaxf(cmax, x);
      }
    cmax = fmaxf(cmax, __shfl_xor(cmax, 16));
    cmax = fmaxf(cmax, __shfl_xor(cmax, 32));
    const float mnew  = fmaxf(m_run, cmax);
    const float alpha = __expf(m_run - mnew);
    float psum = 0.f;
#pragma unroll
    for (int st = 0; st < 4; ++st)
#pragma unroll
      for (int r = 0; r < 4; ++r) {
        const float ev = __expf(p[st][r] - mnew);
        p[st][r] = ev;
        psum += ev;
      }
    psum += __shfl_xor(psum, 16);
    psum += __shfl_xor(psum, 32);
    l_run = l_run * alpha + psum;
    m_run = mnew;

    half4 pf[4];
#pragma unroll
    for (int st = 0; st < 4; ++st) {
      pf[st][0] = (f16)p[st][0]; pf[st][1] = (f16)p[st][1];
      pf[st][2] = (f16)p[st][2]; pf[st][3] = (f16)p[st][3];
      O[st] *= alpha;
    }

    // O^T += V^T · P^T
#pragma unroll
    for (int mi = 0; mi < 4; ++mi) {
      const int row = mi * 16 + l;
#pragma unroll
      for (int ki = 0; ki < 4; ++ki) {
        const int kch = (ki << 1) | (quad >> 1);
        const half4 vf = *(const half4*)&Vt[row * 64 + ((kch ^ lq7) << 3) + ((quad & 1) << 2)];
        O[mi] = __builtin_amdgcn_mfma_f32_16x16x16f16(vf, pf[ki], O[mi], 0, 0, 0);
      }
    }
  }

  const float inv = 1.0f / l_run;
  f16* yp = Y + ((size_t)(b * T_) + qrow) * C_ + h * 64;
#pragma unroll
  for (int mi = 0; mi < 4; ++mi) {
    half4 o;
    o[0] = (f16)(O[mi][0] * inv); o[1] = (f16)(O[mi][1] * inv);
    o[2] = (f16)(O[mi][2] * inv); o[3] = (f16)(O[mi][3] * inv);
    *(half4*)(yp + mi * 16 + quad * 4) = o;
  }
}

// ---------------------------------------------------------------------------
// Kernel 4: out = y @ w_proj + b_proj (fp32 out), same m97-style staging.
// ---------------------------------------------------------------------------
__global__ __launch_bounds__(256) void gemm_proj(
    const f16* __restrict__ A, const f16* __restrict__ Bt,
    const float* __restrict__ bias, float* __restrict__ Out)
{
  __shared__ f16 As[128 * 32];
  __shared__ f16 Bs[128 * 32];
  const int tid  = threadIdx.x;
  const int row0 = blockIdx.y * 128;
  const int col0 = blockIdx.x * 128;
  const int wave = tid >> 6, lane = tid & 63;
  const int l = lane & 15, quad = lane >> 4;
  const int wm = wave >> 1, wn = wave & 1;
  const int sr = tid >> 2, sc = (tid & 3) * 8;

  f32x4 acc[4][4];
#pragma unroll
  for (int mi = 0; mi < 4; ++mi)
#pragma unroll
    for (int ni = 0; ni < 4; ++ni) acc[mi][ni] = (f32x4)0.0f;

  for (int k0 = 0; k0 < C_; k0 += 32) {
    __syncthreads();
#pragma unroll
    for (int p = 0; p < 2; ++p) {
      gld16(A  + (size_t)(row0 + p * 64 + sr) * C_ + k0 + sc, &As[p * 2048 + tid * 8]);
      gld16(Bt + (size_t)(col0 + p * 64 + sr) * C_ + k0 + sc, &Bs[p * 2048 + tid * 8]);
    }
    __syncthreads();

    half8 af[4], bf[4];
#pragma unroll
    for (int mi = 0; mi < 4; ++mi)
      af[mi] = *(const half8*)&As[(wm * 64 + mi * 16 + l) * 32 + quad * 8];
#pragma unroll
    for (int ni = 0; ni < 4; ++ni)
      bf[ni] = *(const half8*)&Bs[(wn * 64 + ni * 16 + l) * 32 + quad * 8];
#pragma unroll
    for (int mi = 0; mi < 4; ++mi)
#pragma unroll
      for (int ni = 0; ni < 4; ++ni)
        acc[mi][ni] = __builtin_amdgcn_mfma_f32_16x16x32_f16(af[mi], bf[ni], acc[mi][ni], 0, 0, 0);
  }

#pragma unroll
  for (int mi = 0; mi < 4; ++mi) {
#pragma unroll
    for (int ni = 0; ni < 4; ++ni) {
#pragma unroll
      for (int r = 0; r < 4; ++r) {
        const int gm = row0 + wm * 64 + mi * 16 + quad * 4 + r;
        const int n  = col0 + wn * 64 + ni * 16 + l;
        Out[(size_t)gm * C_ + n] = acc[mi][ni][r] + bias[n];
      }
    }
  }
}

extern "C" void kernel_launch(void* const* d_in, const int* in_sizes, int n_in,
                              void* d_out, int out_size, void* d_ws, size_t ws_size,
                              hipStream_t stream) {
  const float* x      = (const float*)d_in[0];
  const float* w_attn = (const float*)d_in[1];
  const float* b_attn = (const float*)d_in[2];
  const float* w_proj = (const float*)d_in[3];
  const float* b_proj = (const float*)d_in[4];
  float* out = (float*)d_out;

  const size_t elems = (size_t)BT_ * C_;       // 8,388,608
  f16* x16 = (f16*)d_ws;
  f16* wta = x16 + elems;
  f16* wtp = wta + (size_t)N3C * C_;
  f16* q   = wtp + (size_t)C_ * C_;
  f16* k   = q + elems;
  f16* vt  = k + elems;                        // Vt_g[bh][hd][t]
  f16* y   = vt + elems;                       // total ~92 MB

  cvt_x<<<dim3(elems / 8 / 256), 256, 0, stream>>>(x, x16);
  cvt_transpose<<<dim3(N3C / 64, C_ / 64), 256, 0, stream>>>(w_attn, wta, C_, N3C);
  cvt_transpose<<<dim3(C_ / 64, C_ / 64), 256, 0, stream>>>(w_proj, wtp, C_, C_);
  gemm_qkv<<<dim3(N3C / 128, BT_ / 128), 256, 0, stream>>>(x16, wta, b_attn, q, k, vt);
  rope_qk<<<dim3((B_ * NH_ * T_ * 32) / 256), 256, 0, stream>>>(q, k);
  attn_mfma<<<dim3(32 * 64), 256, 0, stream>>>(q, k, vt, y);
  gemm_proj<<<dim3(C_ / 128, BT_ / 128), 256, 0, stream>>>(y, wtp, b_proj, out);
}

// Round 6
// 277.503 us; speedup vs baseline: 11.2836x; 1.0451x over previous
//
#include <hip/hip_runtime.h>

// Problem constants
#define B_  4
#define T_  2048
#define C_  1024
#define NH_ 16
#define HD_ 64
#define BT_ (B_*T_)   // 8192
#define N3C (3*C_)    // 3072

typedef _Float16 f16;
typedef _Float16 half8 __attribute__((ext_vector_type(8)));
typedef _Float16 half4 __attribute__((ext_vector_type(4)));
typedef float f32x4 __attribute__((ext_vector_type(4)));

// Async global->LDS, 16 B per lane. LDS dest must be lane-linear (base + lane*16).
__device__ __forceinline__ void gld16(const f16* g, f16* l) {
  __builtin_amdgcn_global_load_lds(
      (const __attribute__((address_space(1))) unsigned int*)g,
      (__attribute__((address_space(3))) unsigned int*)l, 16, 0, 0);
}

// ---------------------------------------------------------------------------
// Pre-pass A: x (fp32) -> x16 (f16).
// ---------------------------------------------------------------------------
__global__ __launch_bounds__(256) void cvt_x(const float* __restrict__ X,
                                             f16* __restrict__ X16)
{
  const int i = blockIdx.x * 256 + threadIdx.x;
  const float4 a = ((const float4*)X)[i * 2];
  const float4 b = ((const float4*)X)[i * 2 + 1];
  half8 h;
  h[0] = (f16)a.x; h[1] = (f16)a.y; h[2] = (f16)a.z; h[3] = (f16)a.w;
  h[4] = (f16)b.x; h[5] = (f16)b.y; h[6] = (f16)b.z; h[7] = (f16)b.w;
  ((half8*)X16)[i] = h;
}

// ---------------------------------------------------------------------------
// Pre-pass B: W (K x N fp32) -> Wt (N x K f16).
// ---------------------------------------------------------------------------
__global__ __launch_bounds__(256) void cvt_transpose(
    const float* __restrict__ W, f16* __restrict__ Wt, int K, int N)
{
  __shared__ float Ls[64][65];
  const int tid = threadIdx.x;
  const int n0 = blockIdx.x * 64, k0 = blockIdx.y * 64;
#pragma unroll
  for (int j = 0; j < 4; ++j) {
    const int idx = j * 256 + tid;
    const int r = idx >> 4, c = (idx & 15) * 4;
    const float4 w = *(const float4*)(W + (size_t)(k0 + r) * N + n0 + c);
    Ls[r][c + 0] = w.x; Ls[r][c + 1] = w.y; Ls[r][c + 2] = w.z; Ls[r][c + 3] = w.w;
  }
  __syncthreads();
#pragma unroll
  for (int j = 0; j < 2; ++j) {
    const int idx = j * 256 + tid;
    const int r = idx >> 3, c = (idx & 7) * 8;
    half8 h;
#pragma unroll
    for (int u = 0; u < 8; ++u) h[u] = (f16)Ls[c + u][r];
    *(half8*)(Wt + (size_t)(n0 + r) * K + k0 + c) = h;
  }
}

// ---------------------------------------------------------------------------
// Kernel 1: qkv GEMM + fused RoPE. BK=64, XOR-swizzled LDS (2-way free banks),
// global_load_lds(16B) staging, 16x16x32_f16 MFMA, 2-barrier K-loop (16 iters).
// q/k (with RoPE) -> (B,NH,T,HD); v -> Vt_g[bh][hd][t] transposed.
// LDS layout: chunk position g of row r holds source chunk g ^ (r&7).
// ---------------------------------------------------------------------------
__global__ __launch_bounds__(256) void gemm_qkv(
    const f16* __restrict__ A, const f16* __restrict__ Bt,
    const float* __restrict__ bias,
    f16* __restrict__ Qo, f16* __restrict__ Ko, f16* __restrict__ Vt_g)
{
  __shared__ f16 As[128 * 64];
  __shared__ f16 Bs[128 * 64];
  const int tid  = threadIdx.x;
  const int row0 = blockIdx.y * 128;
  const int col0 = blockIdx.x * 128;
  const int wave = tid >> 6, lane = tid & 63;
  const int l = lane & 15, quad = lane >> 4;
  const int wm = wave >> 1, wn = wave & 1;
  const int sr = tid >> 3;                      // staging row (0..31, +32p)
  const int scs = ((tid & 7) ^ (sr & 7)) * 8;   // swizzled source chunk offset
  const int lq7 = l & 7;

  f32x4 acc[4][4];
#pragma unroll
  for (int mi = 0; mi < 4; ++mi)
#pragma unroll
    for (int ni = 0; ni < 4; ++ni) acc[mi][ni] = (f32x4)0.0f;

  for (int k0 = 0; k0 < C_; k0 += 64) {
    __syncthreads();
#pragma unroll
    for (int p = 0; p < 4; ++p) {
      const int r = p * 32 + sr;
      gld16(A  + (size_t)(row0 + r) * C_ + k0 + scs, &As[p * 2048 + tid * 8]);
      gld16(Bt + (size_t)(col0 + r) * C_ + k0 + scs, &Bs[p * 2048 + tid * 8]);
    }
    __syncthreads();

#pragma unroll
    for (int s = 0; s < 2; ++s) {
      half8 af[4], bf[4];
#pragma unroll
      for (int mi = 0; mi < 4; ++mi)
        af[mi] = *(const half8*)&As[(wm * 64 + mi * 16 + l) * 64 + ((((s << 2) | quad) ^ lq7) << 3)];
#pragma unroll
      for (int ni = 0; ni < 4; ++ni)
        bf[ni] = *(const half8*)&Bs[(wn * 64 + ni * 16 + l) * 64 + ((((s << 2) | quad) ^ lq7) << 3)];
#pragma unroll
      for (int mi = 0; mi < 4; ++mi)
#pragma unroll
        for (int ni = 0; ni < 4; ++ni)
          acc[mi][ni] = __builtin_amdgcn_mfma_f32_16x16x32_f16(af[mi], bf[ni], acc[mi][ni], 0, 0, 0);
    }
  }

  const int region = col0 >> 10;           // 0=q 1=k 2=v
  const int colw = col0 + wn * 64;
  const int h = (colw & 1023) >> 6;
  if (region < 2) {
    // q/k: add bias, apply RoPE in-register (pair d <-> d+32 lives in ni, ni+2),
    // then scatter to (B,NH,T,HD).
    f16* dst = (region == 0) ? Qo : Ko;
    float invf[2];
#pragma unroll
    for (int ni = 0; ni < 2; ++ni) {
      const float fr = (float)(ni * 16 + l);
      invf[ni] = expf(-(2.0f * fr / 64.0f) * 9.210340371976184f);
    }
#pragma unroll
    for (int mi = 0; mi < 4; ++mi) {
#pragma unroll
      for (int r = 0; r < 4; ++r) {
        const int gm = row0 + wm * 64 + mi * 16 + quad * 4 + r;
        const int b = gm >> 11, t = gm & (T_ - 1);
        const size_t base = ((size_t)(b * NH_ + h) * T_ + t) * HD_;
#pragma unroll
        for (int ni = 0; ni < 2; ++ni) {
          const int d = ni * 16 + l;
          const float x1 = acc[mi][ni][r]     + bias[colw + d];
          const float x2 = acc[mi][ni + 2][r] + bias[colw + d + 32];
          float sn, cn;
          sincosf((float)t * invf[ni], &sn, &cn);
          dst[base + d]      = (f16)(x1 * cn - x2 * sn);
          dst[base + d + 32] = (f16)(x2 * cn + x1 * sn);
        }
      }
    }
  } else {
    // V transposed: Vt_g[(bh*64 + d) * T + t], vectorized over r (t-contiguous)
#pragma unroll
    for (int mi = 0; mi < 4; ++mi) {
      const int t0 = row0 + wm * 64 + mi * 16 + quad * 4;
      const int b = t0 >> 11, t = t0 & (T_ - 1);
#pragma unroll
      for (int ni = 0; ni < 4; ++ni) {
        const int d = ni * 16 + l;
        const float bs = bias[colw + d];
        half4 o;
#pragma unroll
        for (int r = 0; r < 4; ++r) o[r] = (f16)(acc[mi][ni][r] + bs);
        *(half4*)(Vt_g + ((size_t)((b * NH_ + h) * HD_ + d)) * T_ + t) = o;
      }
    }
  }
}

// ---------------------------------------------------------------------------
// Kernel 3: MFMA flash attention (unchanged from R5 — verified).
// ---------------------------------------------------------------------------
__global__ __launch_bounds__(256) void attn_mfma(
    const f16* __restrict__ Qg, const f16* __restrict__ Kg,
    const f16* __restrict__ Vt_g, f16* __restrict__ Y)
{
  __shared__ f16 Ks[64 * 64];   // [key][hd], swizzled
  __shared__ f16 Vt[64 * 64];   // [hd][key], swizzled
  const int tid  = threadIdx.x;
  const int qt   = 31 - (blockIdx.x >> 6);
  const int bh   = blockIdx.x & 63;
  const int b    = bh >> 4, h = bh & 15;
  const int wave = tid >> 6, lane = tid & 63;
  const int l    = lane & 15, quad = lane >> 4;
  const int qrow = qt * 64 + wave * 16 + l;

  const f16* qp = Qg + ((size_t)bh * T_ + qrow) * HD_;
  half8 qf[2];
#pragma unroll
  for (int s = 0; s < 2; ++s)
    qf[s] = *(const half8*)(qp + s * 32 + quad * 8);

  f32x4 O[4];
#pragma unroll
  for (int mi = 0; mi < 4; ++mi) O[mi] = (f32x4)0.0f;
  float m_run = -1e30f, l_run = 0.f;

  const f16* kbase  = Kg   + (size_t)bh * T_ * HD_;
  const f16* vtbase = Vt_g + (size_t)bh * HD_ * T_;
  const int lq7 = l & 7;

  for (int kt = 0; kt <= qt; ++kt) {
    __syncthreads();
#pragma unroll
    for (int i = 0; i < 2; ++i) {
      const int r = i * 32 + (tid >> 3);
      const int c = tid & 7;
      const int cs = ((c ^ (r & 7)) << 3);
      const half8 hk = *(const half8*)(kbase + (size_t)(kt * 64 + r) * HD_ + c * 8);
      *(half8*)&Ks[r * 64 + cs] = hk;
      const half8 hv = *(const half8*)(vtbase + (size_t)r * T_ + kt * 64 + c * 8);
      *(half8*)&Vt[r * 64 + cs] = hv;
    }
    __syncthreads();

    f32x4 St[4];
#pragma unroll
    for (int st = 0; st < 4; ++st) {
      f32x4 s_acc = (f32x4)0.0f;
#pragma unroll
      for (int s = 0; s < 2; ++s) {
        const int row = st * 16 + l;
        const half8 af = *(const half8*)&Ks[row * 64 + ((((s << 2) | quad) ^ lq7) << 3)];
        s_acc = __builtin_amdgcn_mfma_f32_16x16x32_f16(af, qf[s], s_acc, 0, 0, 0);
      }
      St[st] = s_acc;
    }

    float p[4][4];
    float cmax = -1e30f;
    const bool diag = (kt == qt);
#pragma unroll
    for (int st = 0; st < 4; ++st)
#pragma unroll
      for (int r = 0; r < 4; ++r) {
        float x = St[st][r] * 0.125f;
        if (diag) {
          const int key = kt * 64 + st * 16 + quad * 4 + r;
          if (key > qrow) x = -1e9f;
        }
        p[st][r] = x;
        cmax = fmaxf(cmax, x);
      }
    cmax = fmaxf(cmax, __shfl_xor(cmax, 16));
    cmax = fmaxf(cmax, __shfl_xor(cmax, 32));
    const float mnew  = fmaxf(m_run, cmax);
    const float alpha = __expf(m_run - mnew);
    float psum = 0.f;
#pragma unroll
    for (int st = 0; st < 4; ++st)
#pragma unroll
      for (int r = 0; r < 4; ++r) {
        const float ev = __expf(p[st][r] - mnew);
        p[st][r] = ev;
        psum += ev;
      }
    psum += __shfl_xor(psum, 16);
    psum += __shfl_xor(psum, 32);
    l_run = l_run * alpha + psum;
    m_run = mnew;

    half4 pf[4];
#pragma unroll
    for (int st = 0; st < 4; ++st) {
      pf[st][0] = (f16)p[st][0]; pf[st][1] = (f16)p[st][1];
      pf[st][2] = (f16)p[st][2]; pf[st][3] = (f16)p[st][3];
      O[st] *= alpha;
    }

#pragma unroll
    for (int mi = 0; mi < 4; ++mi) {
      const int row = mi * 16 + l;
#pragma unroll
      for (int ki = 0; ki < 4; ++ki) {
        const int kch = (ki << 1) | (quad >> 1);
        const half4 vf = *(const half4*)&Vt[row * 64 + ((kch ^ lq7) << 3) + ((quad & 1) << 2)];
        O[mi] = __builtin_amdgcn_mfma_f32_16x16x16f16(vf, pf[ki], O[mi], 0, 0, 0);
      }
    }
  }

  const float inv = 1.0f / l_run;
  f16* yp = Y + ((size_t)(b * T_) + qrow) * C_ + h * 64;
#pragma unroll
  for (int mi = 0; mi < 4; ++mi) {
    half4 o;
    o[0] = (f16)(O[mi][0] * inv); o[1] = (f16)(O[mi][1] * inv);
    o[2] = (f16)(O[mi][2] * inv); o[3] = (f16)(O[mi][3] * inv);
    *(half4*)(yp + mi * 16 + quad * 4) = o;
  }
}

// ---------------------------------------------------------------------------
// Kernel 4: out = y @ w_proj + b_proj (fp32 out). BK=64 + swizzle.
// ---------------------------------------------------------------------------
__global__ __launch_bounds__(256) void gemm_proj(
    const f16* __restrict__ A, const f16* __restrict__ Bt,
    const float* __restrict__ bias, float* __restrict__ Out)
{
  __shared__ f16 As[128 * 64];
  __shared__ f16 Bs[128 * 64];
  const int tid  = threadIdx.x;
  const int row0 = blockIdx.y * 128;
  const int col0 = blockIdx.x * 128;
  const int wave = tid >> 6, lane = tid & 63;
  const int l = lane & 15, quad = lane >> 4;
  const int wm = wave >> 1, wn = wave & 1;
  const int sr = tid >> 3;
  const int scs = ((tid & 7) ^ (sr & 7)) * 8;
  const int lq7 = l & 7;

  f32x4 acc[4][4];
#pragma unroll
  for (int mi = 0; mi < 4; ++mi)
#pragma unroll
    for (int ni = 0; ni < 4; ++ni) acc[mi][ni] = (f32x4)0.0f;

  for (int k0 = 0; k0 < C_; k0 += 64) {
    __syncthreads();
#pragma unroll
    for (int p = 0; p < 4; ++p) {
      const int r = p * 32 + sr;
      gld16(A  + (size_t)(row0 + r) * C_ + k0 + scs, &As[p * 2048 + tid * 8]);
      gld16(Bt + (size_t)(col0 + r) * C_ + k0 + scs, &Bs[p * 2048 + tid * 8]);
    }
    __syncthreads();

#pragma unroll
    for (int s = 0; s < 2; ++s) {
      half8 af[4], bf[4];
#pragma unroll
      for (int mi = 0; mi < 4; ++mi)
        af[mi] = *(const half8*)&As[(wm * 64 + mi * 16 + l) * 64 + ((((s << 2) | quad) ^ lq7) << 3)];
#pragma unroll
      for (int ni = 0; ni < 4; ++ni)
        bf[ni] = *(const half8*)&Bs[(wn * 64 + ni * 16 + l) * 64 + ((((s << 2) | quad) ^ lq7) << 3)];
#pragma unroll
      for (int mi = 0; mi < 4; ++mi)
#pragma unroll
        for (int ni = 0; ni < 4; ++ni)
          acc[mi][ni] = __builtin_amdgcn_mfma_f32_16x16x32_f16(af[mi], bf[ni], acc[mi][ni], 0, 0, 0);
    }
  }

#pragma unroll
  for (int mi = 0; mi < 4; ++mi) {
#pragma unroll
    for (int ni = 0; ni < 4; ++ni) {
#pragma unroll
      for (int r = 0; r < 4; ++r) {
        const int gm = row0 + wm * 64 + mi * 16 + quad * 4 + r;
        const int n  = col0 + wn * 64 + ni * 16 + l;
        Out[(size_t)gm * C_ + n] = acc[mi][ni][r] + bias[n];
      }
    }
  }
}

extern "C" void kernel_launch(void* const* d_in, const int* in_sizes, int n_in,
                              void* d_out, int out_size, void* d_ws, size_t ws_size,
                              hipStream_t stream) {
  const float* x      = (const float*)d_in[0];
  const float* w_attn = (const float*)d_in[1];
  const float* b_attn = (const float*)d_in[2];
  const float* w_proj = (const float*)d_in[3];
  const float* b_proj = (const float*)d_in[4];
  float* out = (float*)d_out;

  const size_t elems = (size_t)BT_ * C_;       // 8,388,608
  f16* x16 = (f16*)d_ws;
  f16* wta = x16 + elems;
  f16* wtp = wta + (size_t)N3C * C_;
  f16* q   = wtp + (size_t)C_ * C_;
  f16* k   = q + elems;
  f16* vt  = k + elems;                        // Vt_g[bh][hd][t]
  f16* y   = vt + elems;                       // total ~92 MB

  cvt_x<<<dim3(elems / 8 / 256), 256, 0, stream>>>(x, x16);
  cvt_transpose<<<dim3(N3C / 64, C_ / 64), 256, 0, stream>>>(w_attn, wta, C_, N3C);
  cvt_transpose<<<dim3(C_ / 64, C_ / 64), 256, 0, stream>>>(w_proj, wtp, C_, C_);
  gemm_qkv<<<dim3(N3C / 128, BT_ / 128), 256, 0, stream>>>(x16, wta, b_attn, q, k, vt);
  attn_mfma<<<dim3(32 * 64), 256, 0, stream>>>(q, k, vt, y);
  gemm_proj<<<dim3(C_ / 128, BT_ / 128), 256, 0, stream>>>(y, wtp, b_proj, out);
}